// Round 1
// baseline (1142.784 us; speedup 1.0000x reference)
//
#include <hip/hip_runtime.h>
#include <math.h>

#define HH 96
#define WW 96
#define NB 4
#define NC 64
#define HW (HH*WW)

// ---------------------------------------------------------------------------
// K0: transpose w_dcn (64,64,3,3) -> wt[g][k][c][co]  (576 x 64)
// ---------------------------------------------------------------------------
__global__ void k_wt(const float* __restrict__ wd, float* __restrict__ wt) {
    int i = blockIdx.x * 256 + threadIdx.x;
    if (i >= 64 * 576) return;
    int co = i & 63;
    int r  = i >> 6;        // (g*9+k)*8 + c
    int c  = r & 7;
    int gk = r >> 3;
    int k  = gk % 9;
    int g  = gk / 9;
    wt[i] = wd[co * 576 + (g * 8 + c) * 9 + k];
}

// ---------------------------------------------------------------------------
// K1: om = conv3x3(offset, w_off) + b_off     (Cin=64 -> Cout=216)
// one thread: 1 pixel x 8 output channels
// ---------------------------------------------------------------------------
__global__ __launch_bounds__(192) void k_conv_off(
    const float* __restrict__ in, const float* __restrict__ wgt,
    const float* __restrict__ bias, float* __restrict__ om) {
    int w   = threadIdx.x;
    int h   = blockIdx.x * 2 + threadIdx.y;
    int cot = blockIdx.y;           // 27 tiles of 8 channels
    int b   = blockIdx.z;
    float acc[8];
#pragma unroll
    for (int o = 0; o < 8; ++o) acc[o] = bias[cot * 8 + o];
    const float* inb = in + b * NC * HW;
    for (int ci = 0; ci < NC; ++ci) {
        float v[9];
#pragma unroll
        for (int dy = 0; dy < 3; ++dy) {
            int y = h + dy - 1;
            bool vy = (y >= 0) && (y < HH);
#pragma unroll
            for (int dx = 0; dx < 3; ++dx) {
                int x = w + dx - 1;
                v[dy * 3 + dx] = (vy && x >= 0 && x < WW) ? inb[ci * HW + y * WW + x] : 0.f;
            }
        }
#pragma unroll
        for (int o = 0; o < 8; ++o) {
            const float* wp = wgt + (cot * 8 + o) * 576 + ci * 9;  // uniform -> s_load
#pragma unroll
            for (int q = 0; q < 9; ++q) acc[o] = fmaf(v[q], wp[q], acc[o]);
        }
    }
    float* outp = om + ((b * 216 + cot * 8) * HH + h) * WW + w;
#pragma unroll
    for (int o = 0; o < 8; ++o) outp[o * HW] = acc[o];
}

// ---------------------------------------------------------------------------
// K2: deformable sampling + einsum + bias + LeakyReLU -> fea
// 8 lanes per pixel (one per deform group g); butterfly-reduce over g.
// ---------------------------------------------------------------------------
__global__ __launch_bounds__(256) void k_deform(
    const float* __restrict__ x, const float* __restrict__ om,
    const float* __restrict__ wt, const float* __restrict__ bias,
    float* __restrict__ fea) {
    int t = threadIdx.x;
    int g = t & 7;
    int p = t >> 3;                       // 32 pixels per block
    int pix = blockIdx.x * 32 + p;        // over B*H*W = 36864
    int b = pix / HW;
    int rem = pix % HW;
    int h = rem / WW;
    int w = rem % WW;

    const float* xb  = x + (b * NC + g * 8) * HW;
    const float* omb = om + b * 216 * HW + h * WW + w;

    float acc[64];
#pragma unroll
    for (int i = 0; i < 64; ++i) acc[i] = 0.f;

    for (int k = 0; k < 9; ++k) {
        int ch = g * 9 + k;
        float oy = omb[ch * HW];
        float ox = omb[(72 + ch) * HW];
        float mv = omb[(144 + ch) * HW];
        float mask = 1.f / (1.f + __expf(-mv));

        float py = (float)(h + (k / 3) - 1) + oy;
        float px = (float)(w + (k % 3) - 1) + ox;
        float y0f = floorf(py), x0f = floorf(px);
        float fy = py - y0f, fx = px - x0f;
        int y0 = (int)y0f, x0 = (int)x0f;
        int y1 = y0 + 1, x1 = x0 + 1;
        int yc0 = min(max(y0, 0), HH - 1), yc1 = min(max(y1, 0), HH - 1);
        int xc0 = min(max(x0, 0), WW - 1), xc1 = min(max(x1, 0), WW - 1);
        float u0 = 1.f - fy, u1 = fy, s0 = 1.f - fx, s1 = fx;
        float w00 = (y0 >= 0 && y0 < HH && x0 >= 0 && x0 < WW) ? u0 * s0 * mask : 0.f;
        float w01 = (y0 >= 0 && y0 < HH && x1 >= 0 && x1 < WW) ? u0 * s1 * mask : 0.f;
        float w10 = (y1 >= 0 && y1 < HH && x0 >= 0 && x0 < WW) ? u1 * s0 * mask : 0.f;
        float w11 = (y1 >= 0 && y1 < HH && x1 >= 0 && x1 < WW) ? u1 * s1 * mask : 0.f;
        int i00 = yc0 * WW + xc0, i01 = yc0 * WW + xc1;
        int i10 = yc1 * WW + xc0, i11 = yc1 * WW + xc1;

        float val[8];
#pragma unroll
        for (int c = 0; c < 8; ++c) {
            const float* xc = xb + c * HW;
            val[c] = w00 * xc[i00] + w01 * xc[i01] + w10 * xc[i10] + w11 * xc[i11];
        }
        const float* wp = wt + (g * 9 + k) * 512;
#pragma unroll
        for (int c = 0; c < 8; ++c) {
            const float4* wv = (const float4*)(wp + c * 64);
#pragma unroll
            for (int q = 0; q < 16; ++q) {
                float4 wq = wv[q];
                acc[q * 4 + 0] = fmaf(val[c], wq.x, acc[q * 4 + 0]);
                acc[q * 4 + 1] = fmaf(val[c], wq.y, acc[q * 4 + 1]);
                acc[q * 4 + 2] = fmaf(val[c], wq.z, acc[q * 4 + 2]);
                acc[q * 4 + 3] = fmaf(val[c], wq.w, acc[q * 4 + 3]);
            }
        }
    }

    // butterfly reduce over the 8 g-lanes (bits 0..2 of lane id)
#pragma unroll
    for (int m = 1; m <= 4; m <<= 1) {
#pragma unroll
        for (int i = 0; i < 64; ++i) acc[i] += __shfl_xor(acc[i], m);
    }

    // each lane stores 8 channels: co = g*8 + j, with bias + LeakyReLU
#pragma unroll
    for (int j = 0; j < 8; ++j) {
        int co = g * 8 + j;
        float d = acc[co] + bias[co];
        float f = (d >= 0.f) ? d : 0.2f * d;
        fea[((b * NC + co) * HH + h) * WW + w] = f;
    }
}

// ---------------------------------------------------------------------------
// K3: out = conv3x3(fea, w_conv1) + b_conv1 + x
// ---------------------------------------------------------------------------
__global__ __launch_bounds__(192) void k_conv1(
    const float* __restrict__ in, const float* __restrict__ wgt,
    const float* __restrict__ bias, const float* __restrict__ xres,
    float* __restrict__ out) {
    int w   = threadIdx.x;
    int h   = blockIdx.x * 2 + threadIdx.y;
    int cot = blockIdx.y;           // 8 tiles of 8 channels
    int b   = blockIdx.z;
    float acc[8];
#pragma unroll
    for (int o = 0; o < 8; ++o) acc[o] = bias[cot * 8 + o];
    const float* inb = in + b * NC * HW;
    for (int ci = 0; ci < NC; ++ci) {
        float v[9];
#pragma unroll
        for (int dy = 0; dy < 3; ++dy) {
            int y = h + dy - 1;
            bool vy = (y >= 0) && (y < HH);
#pragma unroll
            for (int dx = 0; dx < 3; ++dx) {
                int x = w + dx - 1;
                v[dy * 3 + dx] = (vy && x >= 0 && x < WW) ? inb[ci * HW + y * WW + x] : 0.f;
            }
        }
#pragma unroll
        for (int o = 0; o < 8; ++o) {
            const float* wp = wgt + (cot * 8 + o) * 576 + ci * 9;
#pragma unroll
            for (int q = 0; q < 9; ++q) acc[o] = fmaf(v[q], wp[q], acc[o]);
        }
    }
    int cbase = ((b * NC + cot * 8) * HH + h) * WW + w;
#pragma unroll
    for (int o = 0; o < 8; ++o) out[cbase + o * HW] = acc[o] + xres[cbase + o * HW];
}

// ---------------------------------------------------------------------------
extern "C" void kernel_launch(void* const* d_in, const int* in_sizes, int n_in,
                              void* d_out, int out_size, void* d_ws, size_t ws_size,
                              hipStream_t stream) {
    const float* x       = (const float*)d_in[0];
    const float* offset  = (const float*)d_in[1];
    const float* w_off   = (const float*)d_in[2];
    const float* b_off   = (const float*)d_in[3];
    const float* w_dcn   = (const float*)d_in[4];
    const float* b_dcn   = (const float*)d_in[5];
    const float* w_conv1 = (const float*)d_in[6];
    const float* b_conv1 = (const float*)d_in[7];
    float* out = (float*)d_out;

    char* ws = (char*)d_ws;
    float* om  = (float*)ws;                                   // 4*216*9216 f32 = 31,850,496 B
    float* fea = (float*)(ws + 31850496);                      // 4*64*9216 f32 =  9,437,184 B
    float* wt  = (float*)(ws + 31850496 + 9437184);            // 576*64 f32    =    147,456 B

    hipLaunchKernelGGL(k_wt, dim3(144), dim3(256), 0, stream, w_dcn, wt);
    hipLaunchKernelGGL(k_conv_off, dim3(48, 27, 4), dim3(96, 2), 0, stream,
                       offset, w_off, b_off, om);
    hipLaunchKernelGGL(k_deform, dim3(1152), dim3(256), 0, stream,
                       x, om, wt, b_dcn, fea);
    hipLaunchKernelGGL(k_conv1, dim3(48, 8, 4), dim3(96, 2), 0, stream,
                       fea, w_conv1, b_conv1, x, out);
}

// Round 2
// 894.144 us; speedup vs baseline: 1.2781x; 1.2781x over previous
//
#include <hip/hip_runtime.h>
#include <math.h>

#define HH 96
#define WW 96
#define NB 4
#define NC 64
#define HW (HH*WW)

// ---------------------------------------------------------------------------
// K0: transpose w_dcn (64,64,3,3) -> wt[g][k][c][co]  (576 x 64)
// ---------------------------------------------------------------------------
__global__ void k_wt(const float* __restrict__ wd, float* __restrict__ wt) {
    int i = blockIdx.x * 256 + threadIdx.x;
    if (i >= 64 * 576) return;
    int co = i & 63;
    int r  = i >> 6;        // (g*9+k)*8 + c
    int c  = r & 7;
    int gk = r >> 3;
    int k  = gk % 9;
    int g  = gk / 9;
    wt[i] = wd[co * 576 + (g * 8 + c) * 9 + k];
}

// ---------------------------------------------------------------------------
// K1: om = conv3x3(offset, w_off) + b_off     (Cin=64 -> Cout=216)
// ---------------------------------------------------------------------------
__global__ __launch_bounds__(192) void k_conv_off(
    const float* __restrict__ in, const float* __restrict__ wgt,
    const float* __restrict__ bias, float* __restrict__ om) {
    int w   = threadIdx.x;
    int h   = blockIdx.x * 2 + threadIdx.y;
    int cot = blockIdx.y;           // 27 tiles of 8 channels
    int b   = blockIdx.z;
    float acc[8];
#pragma unroll
    for (int o = 0; o < 8; ++o) acc[o] = bias[cot * 8 + o];
    const float* inb = in + b * NC * HW;
    for (int ci = 0; ci < NC; ++ci) {
        float v[9];
#pragma unroll
        for (int dy = 0; dy < 3; ++dy) {
            int y = h + dy - 1;
            bool vy = (y >= 0) && (y < HH);
#pragma unroll
            for (int dx = 0; dx < 3; ++dx) {
                int x = w + dx - 1;
                v[dy * 3 + dx] = (vy && x >= 0 && x < WW) ? inb[ci * HW + y * WW + x] : 0.f;
            }
        }
#pragma unroll
        for (int o = 0; o < 8; ++o) {
            const float* wp = wgt + (cot * 8 + o) * 576 + ci * 9;  // uniform -> s_load
#pragma unroll
            for (int q = 0; q < 9; ++q) acc[o] = fmaf(v[q], wp[q], acc[o]);
        }
    }
    float* outp = om + ((b * 216 + cot * 8) * HH + h) * WW + w;
#pragma unroll
    for (int o = 0; o < 8; ++o) outp[o * HW] = acc[o];
}

// ---------------------------------------------------------------------------
// K2: deformable sampling + einsum + bias + LeakyReLU -> fea
// 8 lanes per pixel (one per deform group g). Each lane accumulates ONLY its
// own 8 output channels (o = g*8+j); cross-group terms arrive by XOR-shuffle
// of the sampled values within the pixel-octet. acc[8] -> no spill.
// ---------------------------------------------------------------------------
__global__ __launch_bounds__(256) void k_deform(
    const float* __restrict__ x, const float* __restrict__ om,
    const float* __restrict__ wt, const float* __restrict__ bias,
    float* __restrict__ fea) {
    int t = threadIdx.x;
    int g = t & 7;
    int p = t >> 3;                       // 32 pixels per block
    int pix = blockIdx.x * 32 + p;        // over B*H*W = 36864
    int b = pix / HW;
    int rem = pix % HW;
    int h = rem / WW;
    int w = rem % WW;

    const float* xb  = x + (b * NC + g * 8) * HW;
    const float* omb = om + b * 216 * HW + h * WW + w;

    float acc[8];
#pragma unroll
    for (int i = 0; i < 8; ++i) acc[i] = 0.f;

    for (int k = 0; k < 9; ++k) {
        int ch = g * 9 + k;
        float oy = omb[ch * HW];
        float ox = omb[(72 + ch) * HW];
        float mv = omb[(144 + ch) * HW];
        float mask = 1.f / (1.f + __expf(-mv));

        float py = (float)(h + (k / 3) - 1) + oy;
        float px = (float)(w + (k % 3) - 1) + ox;
        float y0f = floorf(py), x0f = floorf(px);
        float fy = py - y0f, fx = px - x0f;
        int y0 = (int)y0f, x0 = (int)x0f;
        int y1 = y0 + 1, x1 = x0 + 1;
        int yc0 = min(max(y0, 0), HH - 1), yc1 = min(max(y1, 0), HH - 1);
        int xc0 = min(max(x0, 0), WW - 1), xc1 = min(max(x1, 0), WW - 1);
        float u0 = 1.f - fy, u1 = fy, s0 = 1.f - fx, s1 = fx;
        float w00 = (y0 >= 0 && y0 < HH && x0 >= 0 && x0 < WW) ? u0 * s0 * mask : 0.f;
        float w01 = (y0 >= 0 && y0 < HH && x1 >= 0 && x1 < WW) ? u0 * s1 * mask : 0.f;
        float w10 = (y1 >= 0 && y1 < HH && x0 >= 0 && x0 < WW) ? u1 * s0 * mask : 0.f;
        float w11 = (y1 >= 0 && y1 < HH && x1 >= 0 && x1 < WW) ? u1 * s1 * mask : 0.f;
        int i00 = yc0 * WW + xc0, i01 = yc0 * WW + xc1;
        int i10 = yc1 * WW + xc0, i11 = yc1 * WW + xc1;

        // sampled values for THIS lane's group g, channels c=0..7
        float val[8];
#pragma unroll
        for (int c = 0; c < 8; ++c) {
            const float* xc = xb + c * HW;
            val[c] = w00 * xc[i00] + w01 * xc[i01] + w10 * xc[i10] + w11 * xc[i11];
        }

        // XOR-enumerate the 8 groups: partner lane g^r holds group (g^r)'s vals
#pragma unroll
        for (int r = 0; r < 8; ++r) {
            int gp = g ^ r;                               // source group
            const float* wrow = wt + (gp * 9 + k) * 512 + g * 8;  // + c*64 below
#pragma unroll
            for (int c = 0; c < 8; ++c) {
                float vs = (r == 0) ? val[c] : __shfl_xor(val[c], r);
                float4 w0 = *(const float4*)(wrow + c * 64);
                float4 w1 = *(const float4*)(wrow + c * 64 + 4);
                acc[0] = fmaf(vs, w0.x, acc[0]);
                acc[1] = fmaf(vs, w0.y, acc[1]);
                acc[2] = fmaf(vs, w0.z, acc[2]);
                acc[3] = fmaf(vs, w0.w, acc[3]);
                acc[4] = fmaf(vs, w1.x, acc[4]);
                acc[5] = fmaf(vs, w1.y, acc[5]);
                acc[6] = fmaf(vs, w1.z, acc[6]);
                acc[7] = fmaf(vs, w1.w, acc[7]);
            }
        }
    }

    // lane stores its 8 channels: co = g*8 + j, with bias + LeakyReLU
#pragma unroll
    for (int j = 0; j < 8; ++j) {
        int co = g * 8 + j;
        float d = acc[j] + bias[co];
        float f = (d >= 0.f) ? d : 0.2f * d;
        fea[((b * NC + co) * HH + h) * WW + w] = f;
    }
}

// ---------------------------------------------------------------------------
// K3: out = conv3x3(fea, w_conv1) + b_conv1 + x
// ---------------------------------------------------------------------------
__global__ __launch_bounds__(192) void k_conv1(
    const float* __restrict__ in, const float* __restrict__ wgt,
    const float* __restrict__ bias, const float* __restrict__ xres,
    float* __restrict__ out) {
    int w   = threadIdx.x;
    int h   = blockIdx.x * 2 + threadIdx.y;
    int cot = blockIdx.y;           // 8 tiles of 8 channels
    int b   = blockIdx.z;
    float acc[8];
#pragma unroll
    for (int o = 0; o < 8; ++o) acc[o] = bias[cot * 8 + o];
    const float* inb = in + b * NC * HW;
    for (int ci = 0; ci < NC; ++ci) {
        float v[9];
#pragma unroll
        for (int dy = 0; dy < 3; ++dy) {
            int y = h + dy - 1;
            bool vy = (y >= 0) && (y < HH);
#pragma unroll
            for (int dx = 0; dx < 3; ++dx) {
                int x = w + dx - 1;
                v[dy * 3 + dx] = (vy && x >= 0 && x < WW) ? inb[ci * HW + y * WW + x] : 0.f;
            }
        }
#pragma unroll
        for (int o = 0; o < 8; ++o) {
            const float* wp = wgt + (cot * 8 + o) * 576 + ci * 9;
#pragma unroll
            for (int q = 0; q < 9; ++q) acc[o] = fmaf(v[q], wp[q], acc[o]);
        }
    }
    int cbase = ((b * NC + cot * 8) * HH + h) * WW + w;
#pragma unroll
    for (int o = 0; o < 8; ++o) out[cbase + o * HW] = acc[o] + xres[cbase + o * HW];
}

// ---------------------------------------------------------------------------
extern "C" void kernel_launch(void* const* d_in, const int* in_sizes, int n_in,
                              void* d_out, int out_size, void* d_ws, size_t ws_size,
                              hipStream_t stream) {
    const float* x       = (const float*)d_in[0];
    const float* offset  = (const float*)d_in[1];
    const float* w_off   = (const float*)d_in[2];
    const float* b_off   = (const float*)d_in[3];
    const float* w_dcn   = (const float*)d_in[4];
    const float* b_dcn   = (const float*)d_in[5];
    const float* w_conv1 = (const float*)d_in[6];
    const float* b_conv1 = (const float*)d_in[7];
    float* out = (float*)d_out;

    char* ws = (char*)d_ws;
    float* om  = (float*)ws;                                   // 4*216*9216 f32 = 31,850,496 B
    float* fea = (float*)(ws + 31850496);                      // 4*64*9216 f32 =  9,437,184 B
    float* wt  = (float*)(ws + 31850496 + 9437184);            // 576*64 f32    =    147,456 B

    hipLaunchKernelGGL(k_wt, dim3(144), dim3(256), 0, stream, w_dcn, wt);
    hipLaunchKernelGGL(k_conv_off, dim3(48, 27, 4), dim3(96, 2), 0, stream,
                       offset, w_off, b_off, om);
    hipLaunchKernelGGL(k_deform, dim3(1152), dim3(256), 0, stream,
                       x, om, wt, b_dcn, fea);
    hipLaunchKernelGGL(k_conv1, dim3(48, 8, 4), dim3(96, 2), 0, stream,
                       fea, w_conv1, b_conv1, x, out);
}

// Round 3
// 225.466 us; speedup vs baseline: 5.0685x; 3.9658x over previous
//
#include <hip/hip_runtime.h>
#include <math.h>

#define HH 96
#define WW 96
#define NB 4
#define NC 64
#define HW (HH*WW)
#define NPIX (NB*HW)          // 36864

typedef unsigned short u16;
typedef unsigned int   u32;
typedef __attribute__((ext_vector_type(8))) short bf16x8;
typedef __attribute__((ext_vector_type(4))) float f32x4;

__device__ inline float bf2f(u16 v) { u32 u = ((u32)v) << 16; return __uint_as_float(u); }
__device__ inline u16 f2bf(float f) {
    u32 u = __float_as_uint(f);
    return (u16)((u + 0x7FFFu + ((u >> 16) & 1u)) >> 16);   // RNE
}

// ---------------------------------------------------------------------------
// NCHW f32 (C=64) -> NHWC bf16
// ---------------------------------------------------------------------------
__global__ __launch_bounds__(256) void k_nhwc(const float* __restrict__ src, u16* __restrict__ dst) {
    int pix = blockIdx.x * 256 + threadIdx.x;       // 144 blocks over 36864
    int b = pix / HW, hw = pix % HW;
    const float* s = src + b * 64 * HW + hw;
    uint4* dp = (uint4*)(dst + pix * 64);
#pragma unroll
    for (int q = 0; q < 8; ++q) {
        u32 a0 = (u32)f2bf(s[(q*8+0)*HW]) | ((u32)f2bf(s[(q*8+1)*HW]) << 16);
        u32 a1 = (u32)f2bf(s[(q*8+2)*HW]) | ((u32)f2bf(s[(q*8+3)*HW]) << 16);
        u32 a2 = (u32)f2bf(s[(q*8+4)*HW]) | ((u32)f2bf(s[(q*8+5)*HW]) << 16);
        u32 a3 = (u32)f2bf(s[(q*8+6)*HW]) | ((u32)f2bf(s[(q*8+7)*HW]) << 16);
        dp[q] = make_uint4(a0, a1, a2, a3);
    }
}

// ---------------------------------------------------------------------------
// Repack weights into MFMA B-fragment order:
// dst[((t*NT+cot)*64 + L)*8 + j] = bf16( B[k][co] ),
//   k = t*32 + (L>>4)*8 + j, co = cot*16 + (L&15)
// mode 0 (dcn):  k=(g*9+kk)*8+c -> B = w[co*576 + (g*8+c)*9 + kk]
// mode 1 (q-major convs): k=q*64+ci -> B = w[co*576 + ci*9 + q]; 0 if co>=NCO
// ---------------------------------------------------------------------------
__global__ void k_wtb(const float* __restrict__ w, u16* __restrict__ dst,
                      int NT, int NCO, int mode) {
    int i = blockIdx.x * 256 + threadIdx.x;
    if (i >= 18 * NT * 64 * 8) return;
    int j = i & 7, L = (i >> 3) & 63;
    int cot = (i >> 9) % NT, t = (i >> 9) / NT;
    int k = t * 32 + ((L >> 4) << 3) + j;
    int co = cot * 16 + (L & 15);
    float v = 0.f;
    if (co < NCO) {
        int ci, q;
        if (mode == 0) { int c = k & 7, gk = k >> 3; int kk = gk % 9, g = gk / 9; ci = g*8+c; q = kk; }
        else           { q = k >> 6; ci = k & 63; }
        v = w[co * 576 + ci * 9 + q];
    }
    dst[i] = f2bf(v);
}

// ---------------------------------------------------------------------------
// GEMM off: om[pix][216] (bf16) = im2col(ot)[pix][576] x w_off, + bias
// Implicit im2col: K index r = q*64+c; for K-tile t, q = t>>1 (lane-uniform).
// ---------------------------------------------------------------------------
__global__ __launch_bounds__(256) void k_gemm_off(
    const u16* __restrict__ ot, const u16* __restrict__ wtb,
    const float* __restrict__ bias, u16* __restrict__ om) {
    int wid = threadIdx.x >> 6, L = threadIdx.x & 63;
    int lr = L & 15, lk = L >> 4;
    int pixbase = blockIdx.x * 64 + wid * 16;
    int pixA = pixbase + lr;
    int b = pixbase / HW;
    int hw = pixA % HW, y = hw / WW, x = hw % WW;

    f32x4 acc[14];
#pragma unroll
    for (int i = 0; i < 14; ++i) acc[i] = (f32x4){0.f, 0.f, 0.f, 0.f};

    for (int t = 0; t < 18; ++t) {
        int q = t >> 1;
        int c0 = (t & 1) * 32 + lk * 8;
        int dy = q / 3 - 1, dx = q % 3 - 1;
        int yy = y + dy, xx = x + dx;
        bf16x8 a = {0,0,0,0,0,0,0,0};
        if (yy >= 0 && yy < HH && xx >= 0 && xx < WW)
            a = *(const bf16x8*)(ot + ((b * HH + yy) * WW + xx) * 64 + c0);
        const u16* wp = wtb + (t * 14 * 64 + L) * 8;
#pragma unroll
        for (int cot = 0; cot < 14; ++cot) {
            bf16x8 bf = *(const bf16x8*)(wp + cot * 512);
            acc[cot] = __builtin_amdgcn_mfma_f32_16x16x32_bf16(a, bf, acc[cot], 0, 0, 0);
        }
    }
    int pixC = pixbase + lk * 4;
#pragma unroll
    for (int cot = 0; cot < 14; ++cot) {
        int co = cot * 16 + lr;
        if (co < 216) {
#pragma unroll
            for (int r = 0; r < 4; ++r) {
                float v = acc[cot][r] + bias[co];
                om[(pixC + r) * 216 + co] = f2bf(v);
            }
        }
    }
}

// ---------------------------------------------------------------------------
// Deformable bilinear sampling: sval[pix][ (g*9+kk)*8 + c ] (bf16)
// lane = (g, pixel); 4 corner loads of 8 contiguous channels (NHWC).
// ---------------------------------------------------------------------------
__global__ __launch_bounds__(256) void k_sample(
    const u16* __restrict__ xt, const u16* __restrict__ om,
    u16* __restrict__ sval) {
    int t = threadIdx.x;
    int g = t & 7, p = t >> 3;
    int pix = blockIdx.x * 32 + p;
    int b = pix / HW, hw = pix % HW, h = hw / WW, w = hw % WW;
    const u16* omp = om + pix * 216 + g * 9;
    const u16* xb  = xt + b * HW * 64 + g * 8;

#pragma unroll
    for (int kk = 0; kk < 9; ++kk) {
        float oy = bf2f(omp[kk]);
        float ox = bf2f(omp[72 + kk]);
        float mv = bf2f(omp[144 + kk]);
        float mask = 1.f / (1.f + __expf(-mv));

        float py = (float)(h + kk / 3 - 1) + oy;
        float px = (float)(w + kk % 3 - 1) + ox;
        float y0f = floorf(py), x0f = floorf(px);
        float fy = py - y0f, fx = px - x0f;
        int y0 = (int)y0f, x0 = (int)x0f, y1 = y0 + 1, x1 = x0 + 1;
        int yc0 = min(max(y0, 0), HH-1), yc1 = min(max(y1, 0), HH-1);
        int xc0 = min(max(x0, 0), WW-1), xc1 = min(max(x1, 0), WW-1);
        float u0 = 1.f - fy, u1 = fy, s0 = 1.f - fx, s1 = fx;
        float w00 = (y0 >= 0 && y0 < HH && x0 >= 0 && x0 < WW) ? u0*s0*mask : 0.f;
        float w01 = (y0 >= 0 && y0 < HH && x1 >= 0 && x1 < WW) ? u0*s1*mask : 0.f;
        float w10 = (y1 >= 0 && y1 < HH && x0 >= 0 && x0 < WW) ? u1*s0*mask : 0.f;
        float w11 = (y1 >= 0 && y1 < HH && x1 >= 0 && x1 < WW) ? u1*s1*mask : 0.f;

        uint4 q00 = *(const uint4*)(xb + (yc0*WW + xc0)*64);
        uint4 q01 = *(const uint4*)(xb + (yc0*WW + xc1)*64);
        uint4 q10 = *(const uint4*)(xb + (yc1*WW + xc0)*64);
        uint4 q11 = *(const uint4*)(xb + (yc1*WW + xc1)*64);

        float r[8];
        {
            float a, bb, c, d;
            a=__uint_as_float(q00.x<<16); bb=__uint_as_float(q01.x<<16); c=__uint_as_float(q10.x<<16); d=__uint_as_float(q11.x<<16);
            r[0]=w00*a+w01*bb+w10*c+w11*d;
            a=__uint_as_float(q00.x&0xFFFF0000u); bb=__uint_as_float(q01.x&0xFFFF0000u); c=__uint_as_float(q10.x&0xFFFF0000u); d=__uint_as_float(q11.x&0xFFFF0000u);
            r[1]=w00*a+w01*bb+w10*c+w11*d;
            a=__uint_as_float(q00.y<<16); bb=__uint_as_float(q01.y<<16); c=__uint_as_float(q10.y<<16); d=__uint_as_float(q11.y<<16);
            r[2]=w00*a+w01*bb+w10*c+w11*d;
            a=__uint_as_float(q00.y&0xFFFF0000u); bb=__uint_as_float(q01.y&0xFFFF0000u); c=__uint_as_float(q10.y&0xFFFF0000u); d=__uint_as_float(q11.y&0xFFFF0000u);
            r[3]=w00*a+w01*bb+w10*c+w11*d;
            a=__uint_as_float(q00.z<<16); bb=__uint_as_float(q01.z<<16); c=__uint_as_float(q10.z<<16); d=__uint_as_float(q11.z<<16);
            r[4]=w00*a+w01*bb+w10*c+w11*d;
            a=__uint_as_float(q00.z&0xFFFF0000u); bb=__uint_as_float(q01.z&0xFFFF0000u); c=__uint_as_float(q10.z&0xFFFF0000u); d=__uint_as_float(q11.z&0xFFFF0000u);
            r[5]=w00*a+w01*bb+w10*c+w11*d;
            a=__uint_as_float(q00.w<<16); bb=__uint_as_float(q01.w<<16); c=__uint_as_float(q10.w<<16); d=__uint_as_float(q11.w<<16);
            r[6]=w00*a+w01*bb+w10*c+w11*d;
            a=__uint_as_float(q00.w&0xFFFF0000u); bb=__uint_as_float(q01.w&0xFFFF0000u); c=__uint_as_float(q10.w&0xFFFF0000u); d=__uint_as_float(q11.w&0xFFFF0000u);
            r[7]=w00*a+w01*bb+w10*c+w11*d;
        }
        u32 a0 = (u32)f2bf(r[0]) | ((u32)f2bf(r[1]) << 16);
        u32 a1 = (u32)f2bf(r[2]) | ((u32)f2bf(r[3]) << 16);
        u32 a2 = (u32)f2bf(r[4]) | ((u32)f2bf(r[5]) << 16);
        u32 a3 = (u32)f2bf(r[6]) | ((u32)f2bf(r[7]) << 16);
        *(uint4*)(sval + (size_t)pix * 576 + (g * 9 + kk) * 8) = make_uint4(a0, a1, a2, a3);
    }
}

// ---------------------------------------------------------------------------
// GEMM dcn: fea[pix][64] (bf16, NHWC) = sval[pix][576] x wtb_dcn + bias, LeakyReLU
// ---------------------------------------------------------------------------
__global__ __launch_bounds__(256) void k_gemm_dcn(
    const u16* __restrict__ sval, const u16* __restrict__ wtb,
    const float* __restrict__ bias, u16* __restrict__ fea) {
    int wid = threadIdx.x >> 6, L = threadIdx.x & 63;
    int lr = L & 15, lk = L >> 4;
    int pixbase = blockIdx.x * 64 + wid * 16;
    int pixA = pixbase + lr;

    f32x4 acc[4];
#pragma unroll
    for (int i = 0; i < 4; ++i) acc[i] = (f32x4){0.f, 0.f, 0.f, 0.f};

    for (int t = 0; t < 18; ++t) {
        bf16x8 a = *(const bf16x8*)(sval + (size_t)pixA * 576 + t * 32 + lk * 8);
        const u16* wp = wtb + (t * 4 * 64 + L) * 8;
#pragma unroll
        for (int cot = 0; cot < 4; ++cot) {
            bf16x8 bf = *(const bf16x8*)(wp + cot * 512);
            acc[cot] = __builtin_amdgcn_mfma_f32_16x16x32_bf16(a, bf, acc[cot], 0, 0, 0);
        }
    }
    int pixC = pixbase + lk * 4;
#pragma unroll
    for (int cot = 0; cot < 4; ++cot) {
        int co = cot * 16 + lr;
#pragma unroll
        for (int r = 0; r < 4; ++r) {
            float v = acc[cot][r] + bias[co];
            v = (v >= 0.f) ? v : 0.2f * v;
            fea[(pixC + r) * 64 + co] = f2bf(v);
        }
    }
}

// ---------------------------------------------------------------------------
// GEMM conv1: out[b][co][hw] (f32 NCHW) = im2col(fea) x w_conv1 + bias + x
// ---------------------------------------------------------------------------
__global__ __launch_bounds__(256) void k_gemm_c1(
    const u16* __restrict__ fea, const u16* __restrict__ wtb,
    const float* __restrict__ bias, const float* __restrict__ xres,
    float* __restrict__ out) {
    int wid = threadIdx.x >> 6, L = threadIdx.x & 63;
    int lr = L & 15, lk = L >> 4;
    int pixbase = blockIdx.x * 64 + wid * 16;
    int pixA = pixbase + lr;
    int b = pixbase / HW;
    int hw = pixA % HW, y = hw / WW, x = hw % WW;

    f32x4 acc[4];
#pragma unroll
    for (int i = 0; i < 4; ++i) acc[i] = (f32x4){0.f, 0.f, 0.f, 0.f};

    for (int t = 0; t < 18; ++t) {
        int q = t >> 1;
        int c0 = (t & 1) * 32 + lk * 8;
        int dy = q / 3 - 1, dx = q % 3 - 1;
        int yy = y + dy, xx = x + dx;
        bf16x8 a = {0,0,0,0,0,0,0,0};
        if (yy >= 0 && yy < HH && xx >= 0 && xx < WW)
            a = *(const bf16x8*)(fea + ((b * HH + yy) * WW + xx) * 64 + c0);
        const u16* wp = wtb + (t * 4 * 64 + L) * 8;
#pragma unroll
        for (int cot = 0; cot < 4; ++cot) {
            bf16x8 bf = *(const bf16x8*)(wp + cot * 512);
            acc[cot] = __builtin_amdgcn_mfma_f32_16x16x32_bf16(a, bf, acc[cot], 0, 0, 0);
        }
    }
    int pixC = pixbase + lk * 4;
#pragma unroll
    for (int cot = 0; cot < 4; ++cot) {
        int co = cot * 16 + lr;
#pragma unroll
        for (int r = 0; r < 4; ++r) {
            int hwr = (pixC + r) % HW;
            int idx = (b * 64 + co) * HW + hwr;
            out[idx] = acc[cot][r] + bias[co] + xres[idx];
        }
    }
}

// ---------------------------------------------------------------------------
extern "C" void kernel_launch(void* const* d_in, const int* in_sizes, int n_in,
                              void* d_out, int out_size, void* d_ws, size_t ws_size,
                              hipStream_t stream) {
    const float* x       = (const float*)d_in[0];
    const float* offset  = (const float*)d_in[1];
    const float* w_off   = (const float*)d_in[2];
    const float* b_off   = (const float*)d_in[3];
    const float* w_dcn   = (const float*)d_in[4];
    const float* b_dcn   = (const float*)d_in[5];
    const float* w_conv1 = (const float*)d_in[6];
    const float* b_conv1 = (const float*)d_in[7];
    float* out = (float*)d_out;

    char* ws = (char*)d_ws;
    u16* sval    = (u16*)(ws);                        // 36864*576*2 = 42,467,328
    u16* om      = (u16*)(ws + 42467328);             // 36864*216*2 = 15,925,248
    u16* xt      = (u16*)(ws + 58392576);             // 36864*64*2  =  4,718,592
    u16* ot      = (u16*)(ws + 63111168);             //               4,718,592
    u16* fea     = (u16*)(ws + 67829760);             //               4,718,592
    u16* wtb_off = (u16*)(ws + 72548352);             // 18*14*64*8*2 =  258,048
    u16* wtb_dcn = (u16*)(ws + 72806400);             //                  73,728
    u16* wtb_c1  = (u16*)(ws + 72880128);             //                  73,728

    hipLaunchKernelGGL(k_nhwc, dim3(144), dim3(256), 0, stream, x, xt);
    hipLaunchKernelGGL(k_nhwc, dim3(144), dim3(256), 0, stream, offset, ot);
    hipLaunchKernelGGL(k_wtb, dim3(504), dim3(256), 0, stream, w_off,   wtb_off, 14, 216, 1);
    hipLaunchKernelGGL(k_wtb, dim3(144), dim3(256), 0, stream, w_dcn,   wtb_dcn,  4,  64, 0);
    hipLaunchKernelGGL(k_wtb, dim3(144), dim3(256), 0, stream, w_conv1, wtb_c1,   4,  64, 1);
    hipLaunchKernelGGL(k_gemm_off, dim3(576), dim3(256), 0, stream, ot, wtb_off, b_off, om);
    hipLaunchKernelGGL(k_sample, dim3(1152), dim3(256), 0, stream, xt, om, sval);
    hipLaunchKernelGGL(k_gemm_dcn, dim3(576), dim3(256), 0, stream, sval, wtb_dcn, b_dcn, fea);
    hipLaunchKernelGGL(k_gemm_c1, dim3(576), dim3(256), 0, stream, fea, wtb_c1, b_conv1, x, out);
}

// Round 4
// 177.373 us; speedup vs baseline: 6.4428x; 1.2711x over previous
//
#include <hip/hip_runtime.h>
#include <math.h>

#define HH 96
#define WW 96
#define NB 4
#define NC 64
#define HW (HH*WW)

typedef unsigned short u16;
typedef unsigned int   u32;
typedef __attribute__((ext_vector_type(8))) short bf16x8;
typedef __attribute__((ext_vector_type(4))) float f32x4;

__device__ inline float bf2f(u16 v) { u32 u = ((u32)v) << 16; return __uint_as_float(u); }
__device__ inline u16 f2bf(float f) {
    u32 u = __float_as_uint(f);
    return (u16)((u + 0x7FFFu + ((u >> 16) & 1u)) >> 16);   // RNE
}

// ---------------------------------------------------------------------------
// NCHW f32 (C=64) -> NHWC bf16, two tensors in one launch (blockIdx.y)
// ---------------------------------------------------------------------------
__global__ __launch_bounds__(256) void k_nhwc2(
    const float* __restrict__ s0, const float* __restrict__ s1,
    u16* __restrict__ d0, u16* __restrict__ d1) {
    const float* src = blockIdx.y ? s1 : s0;
    u16* dst = blockIdx.y ? d1 : d0;
    int pix = blockIdx.x * 256 + threadIdx.x;
    int b = pix / HW, hw = pix % HW;
    const float* s = src + b * 64 * HW + hw;
    uint4* dp = (uint4*)(dst + pix * 64);
#pragma unroll
    for (int q = 0; q < 8; ++q) {
        u32 a0 = (u32)f2bf(s[(q*8+0)*HW]) | ((u32)f2bf(s[(q*8+1)*HW]) << 16);
        u32 a1 = (u32)f2bf(s[(q*8+2)*HW]) | ((u32)f2bf(s[(q*8+3)*HW]) << 16);
        u32 a2 = (u32)f2bf(s[(q*8+4)*HW]) | ((u32)f2bf(s[(q*8+5)*HW]) << 16);
        u32 a3 = (u32)f2bf(s[(q*8+6)*HW]) | ((u32)f2bf(s[(q*8+7)*HW]) << 16);
        dp[q] = make_uint4(a0, a1, a2, a3);
    }
}

// ---------------------------------------------------------------------------
// Repack all 3 weight tensors into MFMA B-fragment order (blockIdx.y = which)
// dst[((t*NT+cot)*64 + L)*8 + j] = bf16( B[k][co] ),
//   k = t*32 + (L>>4)*8 + j, co = cot*16 + (L&15)
// ---------------------------------------------------------------------------
__global__ void k_wtb3(const float* __restrict__ w_off, const float* __restrict__ w_dcn,
                       const float* __restrict__ w_c1, u16* __restrict__ d_off,
                       u16* __restrict__ d_dcn, u16* __restrict__ d_c1) {
    int m = blockIdx.y;
    const float* w = (m == 0) ? w_off : ((m == 1) ? w_dcn : w_c1);
    u16* dst = (m == 0) ? d_off : ((m == 1) ? d_dcn : d_c1);
    int NT   = (m == 0) ? 14 : 4;
    int NCO  = (m == 0) ? 216 : 64;
    int mode = (m == 1) ? 0 : 1;     // dcn uses (g,k,c) K-order; convs use (q,ci)
    int n = 18 * NT * 512;
    int i = blockIdx.x * 256 + threadIdx.x;
    if (i >= n) return;
    int j = i & 7, L = (i >> 3) & 63;
    int cot = (i >> 9) % NT, t = (i >> 9) / NT;
    int k = t * 32 + ((L >> 4) << 3) + j;
    int co = cot * 16 + (L & 15);
    float v = 0.f;
    if (co < NCO) {
        int ci, q;
        if (mode == 0) { int c = k & 7, gk = k >> 3; int kk = gk % 9, g = gk / 9; ci = g*8+c; q = kk; }
        else           { q = k >> 6; ci = k & 63; }
        v = w[co * 576 + ci * 9 + q];
    }
    dst[i] = f2bf(v);
}

// ---------------------------------------------------------------------------
// GEMM off: om[pix][216] (bf16) = im2col(ot)[pix][576] x w_off + bias
// B tile (14 KB per K-step) staged in LDS, shared by the 4 waves.
// ---------------------------------------------------------------------------
__global__ __launch_bounds__(256) void k_gemm_off(
    const u16* __restrict__ ot, const u16* __restrict__ wtb,
    const float* __restrict__ bias, u16* __restrict__ om) {
    __shared__ u16 lb[7168];
    int tid = threadIdx.x;
    int wid = tid >> 6, L = tid & 63, lr = L & 15, lk = L >> 4;
    int pixbase = blockIdx.x * 64 + wid * 16;
    int pixA = pixbase + lr;
    int b = pixbase / HW;
    int hw = pixA % HW, y = hw / WW, x = hw % WW;

    f32x4 acc[14];
#pragma unroll
    for (int i = 0; i < 14; ++i) acc[i] = (f32x4){0.f, 0.f, 0.f, 0.f};

    for (int t = 0; t < 18; ++t) {
        if (t) __syncthreads();
        {
            const uint4* s = (const uint4*)(wtb + t * 7168);
            uint4* d = (uint4*)lb;
            for (int i = tid; i < 896; i += 256) d[i] = s[i];
        }
        __syncthreads();
        int q = t >> 1;
        int c0 = (t & 1) * 32 + lk * 8;
        int dy = q / 3 - 1, dx = q % 3 - 1;
        int yy = y + dy, xx = x + dx;
        bf16x8 a = {0,0,0,0,0,0,0,0};
        if (yy >= 0 && yy < HH && xx >= 0 && xx < WW)
            a = *(const bf16x8*)(ot + ((b * HH + yy) * WW + xx) * 64 + c0);
        const u16* wp = lb + L * 8;
#pragma unroll
        for (int cot = 0; cot < 14; ++cot) {
            bf16x8 bf = *(const bf16x8*)(wp + cot * 512);
            acc[cot] = __builtin_amdgcn_mfma_f32_16x16x32_bf16(a, bf, acc[cot], 0, 0, 0);
        }
    }
    int pixC = pixbase + lk * 4;
#pragma unroll
    for (int cot = 0; cot < 14; ++cot) {
        int co = cot * 16 + lr;
        if (co < 216) {
#pragma unroll
            for (int r = 0; r < 4; ++r) {
                float v = acc[cot][r] + bias[co];
                om[(pixC + r) * 216 + co] = f2bf(v);
            }
        }
    }
}

// ---------------------------------------------------------------------------
// Fused deformable sampling + dcn GEMM.
// 64-pixel tile; K=576 split into two 288-halves (groups 0-3 / 4-7).
// Sampled values go to LDS (row 640 B, XOR-swizzled), MFMA reads from LDS.
// ---------------------------------------------------------------------------
__device__ __forceinline__ void sample4(
    const u16* __restrict__ xt, const u16* __restrict__ om,
    u16* __restrict__ sv, int pix, int p, int b, int h, int w, int ga) {
    const u16* omp = om + pix * 216 + ga * 9;
    const u16* xb  = xt + b * HW * 64 + ga * 8;
    int gl = ga & 3;
#pragma unroll
    for (int kk = 0; kk < 9; ++kk) {
        float oy = bf2f(omp[kk]);
        float ox = bf2f(omp[72 + kk]);
        float mv = bf2f(omp[144 + kk]);
        float mask = 1.f / (1.f + __expf(-mv));

        float py = (float)(h + kk / 3 - 1) + oy;
        float px = (float)(w + kk % 3 - 1) + ox;
        float y0f = floorf(py), x0f = floorf(px);
        float fy = py - y0f, fx = px - x0f;
        int y0 = (int)y0f, x0 = (int)x0f, y1 = y0 + 1, x1 = x0 + 1;
        int yc0 = min(max(y0, 0), HH-1), yc1 = min(max(y1, 0), HH-1);
        int xc0 = min(max(x0, 0), WW-1), xc1 = min(max(x1, 0), WW-1);
        float u0 = 1.f - fy, u1 = fy, s0 = 1.f - fx, s1 = fx;
        float w00 = (y0 >= 0 && y0 < HH && x0 >= 0 && x0 < WW) ? u0*s0*mask : 0.f;
        float w01 = (y0 >= 0 && y0 < HH && x1 >= 0 && x1 < WW) ? u0*s1*mask : 0.f;
        float w10 = (y1 >= 0 && y1 < HH && x0 >= 0 && x0 < WW) ? u1*s0*mask : 0.f;
        float w11 = (y1 >= 0 && y1 < HH && x1 >= 0 && x1 < WW) ? u1*s1*mask : 0.f;

        uint4 q00 = *(const uint4*)(xb + (yc0*WW + xc0)*64);
        uint4 q01 = *(const uint4*)(xb + (yc0*WW + xc1)*64);
        uint4 q10 = *(const uint4*)(xb + (yc1*WW + xc0)*64);
        uint4 q11 = *(const uint4*)(xb + (yc1*WW + xc1)*64);

        float r[8];
        {
            float a, bb, c, d;
            a=__uint_as_float(q00.x<<16); bb=__uint_as_float(q01.x<<16); c=__uint_as_float(q10.x<<16); d=__uint_as_float(q11.x<<16);
            r[0]=w00*a+w01*bb+w10*c+w11*d;
            a=__uint_as_float(q00.x&0xFFFF0000u); bb=__uint_as_float(q01.x&0xFFFF0000u); c=__uint_as_float(q10.x&0xFFFF0000u); d=__uint_as_float(q11.x&0xFFFF0000u);
            r[1]=w00*a+w01*bb+w10*c+w11*d;
            a=__uint_as_float(q00.y<<16); bb=__uint_as_float(q01.y<<16); c=__uint_as_float(q10.y<<16); d=__uint_as_float(q11.y<<16);
            r[2]=w00*a+w01*bb+w10*c+w11*d;
            a=__uint_as_float(q00.y&0xFFFF0000u); bb=__uint_as_float(q01.y&0xFFFF0000u); c=__uint_as_float(q10.y&0xFFFF0000u); d=__uint_as_float(q11.y&0xFFFF0000u);
            r[3]=w00*a+w01*bb+w10*c+w11*d;
            a=__uint_as_float(q00.z<<16); bb=__uint_as_float(q01.z<<16); c=__uint_as_float(q10.z<<16); d=__uint_as_float(q11.z<<16);
            r[4]=w00*a+w01*bb+w10*c+w11*d;
            a=__uint_as_float(q00.z&0xFFFF0000u); bb=__uint_as_float(q01.z&0xFFFF0000u); c=__uint_as_float(q10.z&0xFFFF0000u); d=__uint_as_float(q11.z&0xFFFF0000u);
            r[5]=w00*a+w01*bb+w10*c+w11*d;
            a=__uint_as_float(q00.w<<16); bb=__uint_as_float(q01.w<<16); c=__uint_as_float(q10.w<<16); d=__uint_as_float(q11.w<<16);
            r[6]=w00*a+w01*bb+w10*c+w11*d;
            a=__uint_as_float(q00.w&0xFFFF0000u); bb=__uint_as_float(q01.w&0xFFFF0000u); c=__uint_as_float(q10.w&0xFFFF0000u); d=__uint_as_float(q11.w&0xFFFF0000u);
            r[7]=w00*a+w01*bb+w10*c+w11*d;
        }
        u32 a0 = (u32)f2bf(r[0]) | ((u32)f2bf(r[1]) << 16);
        u32 a1 = (u32)f2bf(r[2]) | ((u32)f2bf(r[3]) << 16);
        u32 a2 = (u32)f2bf(r[4]) | ((u32)f2bf(r[5]) << 16);
        u32 a3 = (u32)f2bf(r[6]) | ((u32)f2bf(r[7]) << 16);
        int slot = gl * 9 + kk;                                   // 0..35 (row padded to 40)
        *(uint4*)((char*)sv + p * 640 + ((slot * 16) ^ ((p & 7) << 4))) = make_uint4(a0, a1, a2, a3);
    }
}

__global__ __launch_bounds__(256) void k_sdcn(
    const u16* __restrict__ xt, const u16* __restrict__ om,
    const u16* __restrict__ wtb, const float* __restrict__ bias,
    u16* __restrict__ fea) {
    __shared__ u16 sv[64 * 320];     // 64 rows x 640 B = 40960 B
    int tid = threadIdx.x;
    int pixblk = blockIdx.x * 64;
    int p = tid >> 2, g = tid & 3;
    int pix = pixblk + p;
    int b = pix / HW, hw = pix % HW, h = hw / WW, w = hw % WW;
    int wid = tid >> 6, L = tid & 63, lr = L & 15, lk = L >> 4;
    int prow = wid * 16 + lr;

    f32x4 acc[4];
#pragma unroll
    for (int i = 0; i < 4; ++i) acc[i] = (f32x4){0.f, 0.f, 0.f, 0.f};

    sample4(xt, om, sv, pix, p, b, h, w, g);          // groups 0..3  -> K 0..287
    __syncthreads();
#pragma unroll
    for (int tl = 0; tl < 9; ++tl) {
        bf16x8 a = *(const bf16x8*)((const char*)sv + prow * 640 + (((tl * 4 + lk) * 16) ^ ((prow & 7) << 4)));
        const u16* wp = wtb + (tl * 256 + L) * 8;
#pragma unroll
        for (int cot = 0; cot < 4; ++cot) {
            bf16x8 bf = *(const bf16x8*)(wp + cot * 512);
            acc[cot] = __builtin_amdgcn_mfma_f32_16x16x32_bf16(a, bf, acc[cot], 0, 0, 0);
        }
    }
    __syncthreads();
    sample4(xt, om, sv, pix, p, b, h, w, g + 4);      // groups 4..7  -> K 288..575
    __syncthreads();
#pragma unroll
    for (int tl = 0; tl < 9; ++tl) {
        bf16x8 a = *(const bf16x8*)((const char*)sv + prow * 640 + (((tl * 4 + lk) * 16) ^ ((prow & 7) << 4)));
        const u16* wp = wtb + ((tl + 9) * 256 + L) * 8;
#pragma unroll
        for (int cot = 0; cot < 4; ++cot) {
            bf16x8 bf = *(const bf16x8*)(wp + cot * 512);
            acc[cot] = __builtin_amdgcn_mfma_f32_16x16x32_bf16(a, bf, acc[cot], 0, 0, 0);
        }
    }
    int pixC = pixblk + wid * 16 + lk * 4;
#pragma unroll
    for (int cot = 0; cot < 4; ++cot) {
        int co = cot * 16 + lr;
#pragma unroll
        for (int r = 0; r < 4; ++r) {
            float v = acc[cot][r] + bias[co];
            v = (v >= 0.f) ? v : 0.2f * v;
            fea[(pixC + r) * 64 + co] = f2bf(v);
        }
    }
}

// ---------------------------------------------------------------------------
// GEMM conv1: out (f32 NCHW) = im2col(fea) x w_conv1 + bias + x
// B preloaded in LDS per half (36 KB); LDS-transposed epilogue for
// coalesced NCHW out/xres access.
// ---------------------------------------------------------------------------
__global__ __launch_bounds__(256) void k_gemm_c1(
    const u16* __restrict__ fea, const u16* __restrict__ wtb,
    const float* __restrict__ bias, const float* __restrict__ xres,
    float* __restrict__ out) {
    __shared__ __align__(16) char smraw[36864];
    u16* lb = (u16*)smraw;
    int tid = threadIdx.x;
    int wid = tid >> 6, L = tid & 63, lr = L & 15, lk = L >> 4;
    int pixblk = blockIdx.x * 64;
    int pixbase = pixblk + wid * 16;
    int pixA = pixbase + lr;
    int b = pixblk / HW;
    int hw = pixA % HW, y = hw / WW, x = hw % WW;

    f32x4 acc[4];
#pragma unroll
    for (int i = 0; i < 4; ++i) acc[i] = (f32x4){0.f, 0.f, 0.f, 0.f};

    // half 0: B tiles t=0..8
    {
        const uint4* s = (const uint4*)wtb;
        uint4* d = (uint4*)lb;
#pragma unroll
        for (int i = 0; i < 9; ++i) d[tid + i * 256] = s[tid + i * 256];
    }
    __syncthreads();
    for (int half = 0; half < 2; ++half) {
        int tbase = half * 9;
#pragma unroll
        for (int tl = 0; tl < 9; ++tl) {
            int t = tbase + tl;
            int q = t >> 1;
            int c0 = (t & 1) * 32 + lk * 8;
            int dy = q / 3 - 1, dx = q % 3 - 1;
            int yy = y + dy, xx = x + dx;
            bf16x8 a = {0,0,0,0,0,0,0,0};
            if (yy >= 0 && yy < HH && xx >= 0 && xx < WW)
                a = *(const bf16x8*)(fea + ((b * HH + yy) * WW + xx) * 64 + c0);
            const u16* wp = lb + (tl * 256 + L) * 8;
#pragma unroll
            for (int cot = 0; cot < 4; ++cot) {
                bf16x8 bf = *(const bf16x8*)(wp + cot * 512);
                acc[cot] = __builtin_amdgcn_mfma_f32_16x16x32_bf16(a, bf, acc[cot], 0, 0, 0);
            }
        }
        __syncthreads();
        if (half == 0) {
            const uint4* s = (const uint4*)(wtb + 18432);
            uint4* d = (uint4*)lb;
#pragma unroll
            for (int i = 0; i < 9; ++i) d[tid + i * 256] = s[tid + i * 256];
            __syncthreads();
        }
    }
    // epilogue: stage C tile in LDS (row pad 66 f32), coalesced NCHW writes
    float* ob = (float*)smraw;
#pragma unroll
    for (int cot = 0; cot < 4; ++cot) {
#pragma unroll
        for (int r = 0; r < 4; ++r)
            ob[(wid * 16 + lk * 4 + r) * 66 + cot * 16 + lr] = acc[cot][r];
    }
    __syncthreads();
    int p = tid & 63, cg = tid >> 6;
    int hw0 = pixblk % HW;
#pragma unroll
    for (int i = 0; i < 16; ++i) {
        int co = cg * 16 + i;
        int idx = (b * 64 + co) * HW + hw0 + p;
        out[idx] = ob[p * 66 + co] + bias[co] + xres[idx];
    }
}

// ---------------------------------------------------------------------------
extern "C" void kernel_launch(void* const* d_in, const int* in_sizes, int n_in,
                              void* d_out, int out_size, void* d_ws, size_t ws_size,
                              hipStream_t stream) {
    const float* x       = (const float*)d_in[0];
    const float* offset  = (const float*)d_in[1];
    const float* w_off   = (const float*)d_in[2];
    const float* b_off   = (const float*)d_in[3];
    const float* w_dcn   = (const float*)d_in[4];
    const float* b_dcn   = (const float*)d_in[5];
    const float* w_conv1 = (const float*)d_in[6];
    const float* b_conv1 = (const float*)d_in[7];
    float* out = (float*)d_out;

    char* ws = (char*)d_ws;
    u16* om      = (u16*)(ws);                        // 36864*216*2 = 15,925,248
    u16* xt      = (u16*)(ws + 15925248);             // 36864*64*2  =  4,718,592
    u16* ot      = (u16*)(ws + 20643840);             //               4,718,592
    u16* fea     = (u16*)(ws + 25362432);             //               4,718,592
    u16* wtb_off = (u16*)(ws + 30081024);             // 18*14*512*2 =   258,048
    u16* wtb_dcn = (u16*)(ws + 30339072);             //                  73,728
    u16* wtb_c1  = (u16*)(ws + 30412800);             //                  73,728

    hipLaunchKernelGGL(k_nhwc2, dim3(144, 2), dim3(256), 0, stream, x, offset, xt, ot);
    hipLaunchKernelGGL(k_wtb3, dim3(504, 3), dim3(256), 0, stream,
                       w_off, w_dcn, w_conv1, wtb_off, wtb_dcn, wtb_c1);
    hipLaunchKernelGGL(k_gemm_off, dim3(576), dim3(256), 0, stream, ot, wtb_off, b_off, om);
    hipLaunchKernelGGL(k_sdcn, dim3(576), dim3(256), 0, stream, xt, om, wtb_dcn, b_dcn, fea);
    hipLaunchKernelGGL(k_gemm_c1, dim3(576), dim3(256), 0, stream, fea, wtb_c1, b_conv1, x, out);
}

// Round 5
// 164.863 us; speedup vs baseline: 6.9317x; 1.0759x over previous
//
#include <hip/hip_runtime.h>
#include <math.h>

#define HH 96
#define WW 96
#define NB 4
#define NC 64
#define HW (HH*WW)

typedef unsigned short u16;
typedef unsigned int   u32;
typedef __attribute__((ext_vector_type(8))) short bf16x8;
typedef __attribute__((ext_vector_type(4))) float f32x4;

__device__ inline float bf2f(u16 v) { u32 u = ((u32)v) << 16; return __uint_as_float(u); }
__device__ inline u16 f2bf(float f) {
    u32 u = __float_as_uint(f);
    return (u16)((u + 0x7FFFu + ((u >> 16) & 1u)) >> 16);   // RNE
}
__device__ __forceinline__ float elemf(const u32* a, int i) {  // u16 elem i as bf16->f32
    u32 v = a[i >> 1];
    v = (i & 1) ? (v & 0xFFFF0000u) : (v << 16);
    return __uint_as_float(v);
}

// ---------------------------------------------------------------------------
// k_prep: NCHW->NHWC bf16 for x & offset (blocks 0..287) + weight repack into
// MFMA B-fragment order for all 3 weights (blocks 288..1079).
// B-frag: dst[((t*NT+cot)*64+L)*8+j] = B[k][co], k=t*32+(L>>4)*8+j, co=cot*16+(L&15)
// ---------------------------------------------------------------------------
__global__ __launch_bounds__(256) void k_prep(
    const float* __restrict__ x, const float* __restrict__ offset,
    const float* __restrict__ w_off, const float* __restrict__ w_dcn,
    const float* __restrict__ w_c1,
    u16* __restrict__ xt, u16* __restrict__ ot,
    u16* __restrict__ d_off, u16* __restrict__ d_dcn, u16* __restrict__ d_c1) {
    int bx = blockIdx.x;
    int tid = threadIdx.x;
    if (bx < 288) {
        const float* src = (bx < 144) ? x : offset;
        u16* dst = (bx < 144) ? xt : ot;
        int pix = (bx % 144) * 256 + tid;
        int b = pix / HW, hw = pix % HW;
        const float* s = src + b * 64 * HW + hw;
        uint4* dp = (uint4*)(dst + pix * 64);
#pragma unroll
        for (int q = 0; q < 8; ++q) {
            u32 a0 = (u32)f2bf(s[(q*8+0)*HW]) | ((u32)f2bf(s[(q*8+1)*HW]) << 16);
            u32 a1 = (u32)f2bf(s[(q*8+2)*HW]) | ((u32)f2bf(s[(q*8+3)*HW]) << 16);
            u32 a2 = (u32)f2bf(s[(q*8+4)*HW]) | ((u32)f2bf(s[(q*8+5)*HW]) << 16);
            u32 a3 = (u32)f2bf(s[(q*8+6)*HW]) | ((u32)f2bf(s[(q*8+7)*HW]) << 16);
            dp[q] = make_uint4(a0, a1, a2, a3);
        }
        return;
    }
    int rel = bx - 288;
    int m, i0;
    if (rel < 504)      { m = 0; i0 = rel * 256; }
    else if (rel < 648) { m = 1; i0 = (rel - 504) * 256; }
    else                { m = 2; i0 = (rel - 648) * 256; }
    const float* w = (m == 0) ? w_off : ((m == 1) ? w_dcn : w_c1);
    u16* dst = (m == 0) ? d_off : ((m == 1) ? d_dcn : d_c1);
    int NT   = (m == 0) ? 14 : 4;
    int NCO  = (m == 0) ? 216 : 64;
    int i = i0 + tid;
    if (i >= 18 * NT * 512) return;
    int j = i & 7, L = (i >> 3) & 63;
    int cot = (i >> 9) % NT, t = (i >> 9) / NT;
    int k = t * 32 + ((L >> 4) << 3) + j;
    int co = cot * 16 + (L & 15);
    float v = 0.f;
    if (co < NCO) {
        int ci, q;
        if (m == 1) { int c = k & 7, gk = k >> 3; int kk = gk % 9, g = gk / 9; ci = g*8+c; q = kk; }
        else        { q = k >> 6; ci = k & 63; }
        v = w[co * 576 + ci * 9 + q];
    }
    dst[i] = f2bf(v);
}

// ---------------------------------------------------------------------------
// GEMM off: im2col(ot)[pix][576] x w_off + bias -> omr[pix][g][32]
// slots per g: 0-8 oy, 9-17 ox, 18-26 sigmoid(mask). B staged in LDS per K-step.
// ---------------------------------------------------------------------------
__global__ __launch_bounds__(256) void k_gemm_off(
    const u16* __restrict__ ot, const u16* __restrict__ wtb,
    const float* __restrict__ bias, u16* __restrict__ omr) {
    __shared__ u16 lb[7168];
    int tid = threadIdx.x;
    int wid = tid >> 6, L = tid & 63, lr = L & 15, lk = L >> 4;
    int pixbase = blockIdx.x * 64 + wid * 16;
    int pixA = pixbase + lr;
    int b = pixbase / HW;
    int hw = pixA % HW, y = hw / WW, x = hw % WW;

    f32x4 acc[14];
#pragma unroll
    for (int i = 0; i < 14; ++i) acc[i] = (f32x4){0.f, 0.f, 0.f, 0.f};

    for (int t = 0; t < 18; ++t) {
        if (t) __syncthreads();
        {
            const uint4* s = (const uint4*)(wtb + t * 7168);
            uint4* d = (uint4*)lb;
            for (int i = tid; i < 896; i += 256) d[i] = s[i];
        }
        __syncthreads();
        int q = t >> 1;
        int c0 = (t & 1) * 32 + lk * 8;
        int dy = q / 3 - 1, dx = q % 3 - 1;
        int yy = y + dy, xx = x + dx;
        bf16x8 a = {0,0,0,0,0,0,0,0};
        if (yy >= 0 && yy < HH && xx >= 0 && xx < WW)
            a = *(const bf16x8*)(ot + ((b * HH + yy) * WW + xx) * 64 + c0);
        const u16* wp = lb + L * 8;
#pragma unroll
        for (int cot = 0; cot < 14; ++cot) {
            bf16x8 bf = *(const bf16x8*)(wp + cot * 512);
            acc[cot] = __builtin_amdgcn_mfma_f32_16x16x32_bf16(a, bf, acc[cot], 0, 0, 0);
        }
    }
    int pixC = pixbase + lk * 4;
#pragma unroll
    for (int cot = 0; cot < 14; ++cot) {
        int co = cot * 16 + lr;
        if (co < 216) {
            int cls = co / 72;          // 0:oy 1:ox 2:mask
            int c   = co % 72;
            int g   = c / 9, kk = c % 9;
            int slot = g * 32 + cls * 9 + kk;
#pragma unroll
            for (int r = 0; r < 4; ++r) {
                float v = acc[cot][r] + bias[co];
                if (cls == 2) v = 1.f / (1.f + __expf(-v));
                omr[(pixC + r) * 256 + slot] = f2bf(v);
            }
        }
    }
}

// ---------------------------------------------------------------------------
// Fused deformable sampling + dcn GEMM. 32-pixel tile, single sample phase:
// lane = (pixel p, group g) covers all 8 groups; LDS rows 1152 B, XOR-swizzled.
// ---------------------------------------------------------------------------
__global__ __launch_bounds__(256) void k_sdcn(
    const u16* __restrict__ xt, const u16* __restrict__ omr,
    const u16* __restrict__ wtb, const float* __restrict__ bias,
    u16* __restrict__ fea) {
    __shared__ u16 sv[32 * 576];     // 36864 B
    int tid = threadIdx.x;
    int pixblk = blockIdx.x * 32;
    int p = tid >> 3, g = tid & 7;
    int pix = pixblk + p;
    int b = pixblk / HW;
    int hw = pix % HW, h = hw / WW, w = hw % WW;

    // ---- sample: all 9 taps for (pixel p, group g) ----
    {
        const u16* xb = xt + b * HW * 64 + g * 8;
        const uint4* op = (const uint4*)(omr + (size_t)pix * 256 + g * 32);
        uint4 o0 = op[0], o1 = op[1], o2 = op[2], o3 = op[3];
        u32 oa[16] = {o0.x,o0.y,o0.z,o0.w, o1.x,o1.y,o1.z,o1.w,
                      o2.x,o2.y,o2.z,o2.w, o3.x,o3.y,o3.z,o3.w};
#pragma unroll
        for (int kk = 0; kk < 9; ++kk) {
            float oy   = elemf(oa, kk);
            float ox   = elemf(oa, 9 + kk);
            float mask = elemf(oa, 18 + kk);

            float py = (float)(h + kk / 3 - 1) + oy;
            float px = (float)(w + kk % 3 - 1) + ox;
            float y0f = floorf(py), x0f = floorf(px);
            float fy = py - y0f, fx = px - x0f;
            int y0 = (int)y0f, x0 = (int)x0f, y1 = y0 + 1, x1 = x0 + 1;
            int yc0 = min(max(y0, 0), HH-1), yc1 = min(max(y1, 0), HH-1);
            int xc0 = min(max(x0, 0), WW-1), xc1 = min(max(x1, 0), WW-1);
            float u0 = 1.f - fy, u1 = fy, s0 = 1.f - fx, s1 = fx;
            float w00 = (y0 >= 0 && y0 < HH && x0 >= 0 && x0 < WW) ? u0*s0*mask : 0.f;
            float w01 = (y0 >= 0 && y0 < HH && x1 >= 0 && x1 < WW) ? u0*s1*mask : 0.f;
            float w10 = (y1 >= 0 && y1 < HH && x0 >= 0 && x0 < WW) ? u1*s0*mask : 0.f;
            float w11 = (y1 >= 0 && y1 < HH && x1 >= 0 && x1 < WW) ? u1*s1*mask : 0.f;

            uint4 q00 = *(const uint4*)(xb + (yc0*WW + xc0)*64);
            uint4 q01 = *(const uint4*)(xb + (yc0*WW + xc1)*64);
            uint4 q10 = *(const uint4*)(xb + (yc1*WW + xc0)*64);
            uint4 q11 = *(const uint4*)(xb + (yc1*WW + xc1)*64);

            float r[8];
            {
                float a, bb, c, d;
                a=__uint_as_float(q00.x<<16); bb=__uint_as_float(q01.x<<16); c=__uint_as_float(q10.x<<16); d=__uint_as_float(q11.x<<16);
                r[0]=w00*a+w01*bb+w10*c+w11*d;
                a=__uint_as_float(q00.x&0xFFFF0000u); bb=__uint_as_float(q01.x&0xFFFF0000u); c=__uint_as_float(q10.x&0xFFFF0000u); d=__uint_as_float(q11.x&0xFFFF0000u);
                r[1]=w00*a+w01*bb+w10*c+w11*d;
                a=__uint_as_float(q00.y<<16); bb=__uint_as_float(q01.y<<16); c=__uint_as_float(q10.y<<16); d=__uint_as_float(q11.y<<16);
                r[2]=w00*a+w01*bb+w10*c+w11*d;
                a=__uint_as_float(q00.y&0xFFFF0000u); bb=__uint_as_float(q01.y&0xFFFF0000u); c=__uint_as_float(q10.y&0xFFFF0000u); d=__uint_as_float(q11.y&0xFFFF0000u);
                r[3]=w00*a+w01*bb+w10*c+w11*d;
                a=__uint_as_float(q00.z<<16); bb=__uint_as_float(q01.z<<16); c=__uint_as_float(q10.z<<16); d=__uint_as_float(q11.z<<16);
                r[4]=w00*a+w01*bb+w10*c+w11*d;
                a=__uint_as_float(q00.z&0xFFFF0000u); bb=__uint_as_float(q01.z&0xFFFF0000u); c=__uint_as_float(q10.z&0xFFFF0000u); d=__uint_as_float(q11.z&0xFFFF0000u);
                r[5]=w00*a+w01*bb+w10*c+w11*d;
                a=__uint_as_float(q00.w<<16); bb=__uint_as_float(q01.w<<16); c=__uint_as_float(q10.w<<16); d=__uint_as_float(q11.w<<16);
                r[6]=w00*a+w01*bb+w10*c+w11*d;
                a=__uint_as_float(q00.w&0xFFFF0000u); bb=__uint_as_float(q01.w&0xFFFF0000u); c=__uint_as_float(q10.w&0xFFFF0000u); d=__uint_as_float(q11.w&0xFFFF0000u);
                r[7]=w00*a+w01*bb+w10*c+w11*d;
            }
            u32 a0 = (u32)f2bf(r[0]) | ((u32)f2bf(r[1]) << 16);
            u32 a1 = (u32)f2bf(r[2]) | ((u32)f2bf(r[3]) << 16);
            u32 a2 = (u32)f2bf(r[4]) | ((u32)f2bf(r[5]) << 16);
            u32 a3 = (u32)f2bf(r[6]) | ((u32)f2bf(r[7]) << 16);
            int slot = g * 9 + kk;
            *(uint4*)((char*)sv + p * 1152 + ((slot * 16) ^ ((p & 7) << 4))) = make_uint4(a0, a1, a2, a3);
        }
    }
    __syncthreads();

    // ---- MFMA: M=32 x K=576 x N=64; wave (wid): pixels (wid&1)*16.., cots (wid>>1)*2.. ----
    int wid = tid >> 6, L = tid & 63, lr = L & 15, lk = L >> 4;
    int pbase = (wid & 1) * 16, cbase = (wid >> 1) * 2;
    int arow = pbase + lr;

    f32x4 acc[2];
    acc[0] = (f32x4){0.f, 0.f, 0.f, 0.f};
    acc[1] = (f32x4){0.f, 0.f, 0.f, 0.f};
#pragma unroll
    for (int t = 0; t < 18; ++t) {
        bf16x8 a = *(const bf16x8*)((const char*)sv + arow * 1152 + (((t * 4 + lk) * 16) ^ ((arow & 7) << 4)));
#pragma unroll
        for (int ct = 0; ct < 2; ++ct) {
            bf16x8 bf = *(const bf16x8*)(wtb + ((t * 4 + cbase + ct) * 64 + L) * 8);
            acc[ct] = __builtin_amdgcn_mfma_f32_16x16x32_bf16(a, bf, acc[ct], 0, 0, 0);
        }
    }
#pragma unroll
    for (int ct = 0; ct < 2; ++ct) {
        int co = (cbase + ct) * 16 + lr;
        float bs = bias[co];
#pragma unroll
        for (int r = 0; r < 4; ++r) {
            float v = acc[ct][r] + bs;
            v = (v >= 0.f) ? v : 0.2f * v;
            fea[(pixblk + pbase + lk * 4 + r) * 64 + co] = f2bf(v);
        }
    }
}

// ---------------------------------------------------------------------------
// GEMM conv1: out (f32 NCHW) = im2col(fea) x w_conv1 + bias + x
// ---------------------------------------------------------------------------
__global__ __launch_bounds__(256) void k_gemm_c1(
    const u16* __restrict__ fea, const u16* __restrict__ wtb,
    const float* __restrict__ bias, const float* __restrict__ xres,
    float* __restrict__ out) {
    __shared__ __align__(16) char smraw[36864];
    u16* lb = (u16*)smraw;
    int tid = threadIdx.x;
    int wid = tid >> 6, L = tid & 63, lr = L & 15, lk = L >> 4;
    int pixblk = blockIdx.x * 64;
    int pixbase = pixblk + wid * 16;
    int pixA = pixbase + lr;
    int b = pixblk / HW;
    int hw = pixA % HW, y = hw / WW, x = hw % WW;

    f32x4 acc[4];
#pragma unroll
    for (int i = 0; i < 4; ++i) acc[i] = (f32x4){0.f, 0.f, 0.f, 0.f};

    {
        const uint4* s = (const uint4*)wtb;
        uint4* d = (uint4*)lb;
#pragma unroll
        for (int i = 0; i < 9; ++i) d[tid + i * 256] = s[tid + i * 256];
    }
    __syncthreads();
    for (int half = 0; half < 2; ++half) {
        int tbase = half * 9;
#pragma unroll
        for (int tl = 0; tl < 9; ++tl) {
            int t = tbase + tl;
            int q = t >> 1;
            int c0 = (t & 1) * 32 + lk * 8;
            int dy = q / 3 - 1, dx = q % 3 - 1;
            int yy = y + dy, xx = x + dx;
            bf16x8 a = {0,0,0,0,0,0,0,0};
            if (yy >= 0 && yy < HH && xx >= 0 && xx < WW)
                a = *(const bf16x8*)(fea + ((b * HH + yy) * WW + xx) * 64 + c0);
            const u16* wp = lb + (tl * 256 + L) * 8;
#pragma unroll
            for (int cot = 0; cot < 4; ++cot) {
                bf16x8 bf = *(const bf16x8*)(wp + cot * 512);
                acc[cot] = __builtin_amdgcn_mfma_f32_16x16x32_bf16(a, bf, acc[cot], 0, 0, 0);
            }
        }
        __syncthreads();
        if (half == 0) {
            const uint4* s = (const uint4*)(wtb + 18432);
            uint4* d = (uint4*)lb;
#pragma unroll
            for (int i = 0; i < 9; ++i) d[tid + i * 256] = s[tid + i * 256];
            __syncthreads();
        }
    }
    float* ob = (float*)smraw;
#pragma unroll
    for (int cot = 0; cot < 4; ++cot) {
#pragma unroll
        for (int r = 0; r < 4; ++r)
            ob[(wid * 16 + lk * 4 + r) * 66 + cot * 16 + lr] = acc[cot][r];
    }
    __syncthreads();
    int p = tid & 63, cg = tid >> 6;
    int hw0 = pixblk % HW;
#pragma unroll
    for (int i = 0; i < 16; ++i) {
        int co = cg * 16 + i;
        int idx = (b * 64 + co) * HW + hw0 + p;
        out[idx] = ob[p * 66 + co] + bias[co] + xres[idx];
    }
}

// ---------------------------------------------------------------------------
extern "C" void kernel_launch(void* const* d_in, const int* in_sizes, int n_in,
                              void* d_out, int out_size, void* d_ws, size_t ws_size,
                              hipStream_t stream) {
    const float* x       = (const float*)d_in[0];
    const float* offset  = (const float*)d_in[1];
    const float* w_off   = (const float*)d_in[2];
    const float* b_off   = (const float*)d_in[3];
    const float* w_dcn   = (const float*)d_in[4];
    const float* b_dcn   = (const float*)d_in[5];
    const float* w_conv1 = (const float*)d_in[6];
    const float* b_conv1 = (const float*)d_in[7];
    float* out = (float*)d_out;

    char* ws = (char*)d_ws;
    u16* omr     = (u16*)(ws);                        // 36864*256*2 = 18,874,368
    u16* xt      = (u16*)(ws + 18874368);             //  4,718,592
    u16* ot      = (u16*)(ws + 23592960);             //  4,718,592
    u16* fea     = (u16*)(ws + 28311552);             //  4,718,592
    u16* wtb_off = (u16*)(ws + 33030144);             //    258,048
    u16* wtb_dcn = (u16*)(ws + 33288192);             //     73,728
    u16* wtb_c1  = (u16*)(ws + 33361920);             //     73,728

    hipLaunchKernelGGL(k_prep, dim3(1080), dim3(256), 0, stream,
                       x, offset, w_off, w_dcn, w_conv1, xt, ot, wtb_off, wtb_dcn, wtb_c1);
    hipLaunchKernelGGL(k_gemm_off, dim3(576), dim3(256), 0, stream, ot, wtb_off, b_off, omr);
    hipLaunchKernelGGL(k_sdcn, dim3(1152), dim3(256), 0, stream, xt, omr, wtb_dcn, b_dcn, fea);
    hipLaunchKernelGGL(k_gemm_c1, dim3(576), dim3(256), 0, stream, fea, wtb_c1, b_conv1, x, out);
}